// Round 8
// baseline (279.654 us; speedup 1.0000x reference)
//
#include <hip/hip_runtime.h>
#include <cstddef>
#include <cstdint>

#define NN   100000   // nodes
#define NR   4        // relations
#define NE   160000   // edges per relation
#define SCAN_B 1024

typedef short bf16x8 __attribute__((ext_vector_type(8)));
typedef float f32x4  __attribute__((ext_vector_type(4)));

__device__ __forceinline__ unsigned short f2bf(float f) {  // RNE f32->bf16
  union { float f; unsigned u; } v; v.f = f;
  unsigned r = v.u + 0x7fffu + ((v.u >> 16) & 1u);
  return (unsigned short)(r >> 16);
}
__device__ __forceinline__ float bf2f(unsigned short h) {
  union { unsigned u; float f; } v; v.u = ((unsigned)h) << 16;
  return v.f;
}

// async global->LDS, 16B per lane, linear LDS dest
__device__ __forceinline__ void gll16(const unsigned short* g, unsigned short* l) {
  __builtin_amdgcn_global_load_lds(
      (const __attribute__((address_space(1))) void*)g,
      (__attribute__((address_space(3))) void*)l, 16, 0, 0);
}

// ---------------------------------------------------------------- degree counts (R5 verbatim)
__global__ __launch_bounds__(256) void count_k(const int* __restrict__ edges,
                                               int* __restrict__ cnt_out,
                                               int* __restrict__ cnt_in) {
  const int r = blockIdx.y;
  const int e = blockIdx.x * 256 + threadIdx.x;
  if (e >= NE) return;
  const int s = edges[(size_t)r * 2 * NE + e];
  const int d = edges[(size_t)r * 2 * NE + NE + e];
  atomicAdd(&cnt_out[(size_t)r * NN + s], 1);
  atomicAdd(&cnt_in[(size_t)r * NN + d], 1);
}

__global__ __launch_bounds__(256) void rs_k(const int* __restrict__ cnt,
                                            float* __restrict__ rs, int n) {
  const int i = blockIdx.x * 256 + threadIdx.x;
  if (i < n) rs[i] = rsqrtf(fmaxf((float)cnt[i], 1.0f));
}

// ---------------------------------------------------------------- combined-CSR scan (R5 verbatim)
__global__ __launch_bounds__(256) void scan1_k(const int* __restrict__ cnt_in,
                                               int* __restrict__ excl,
                                               int* __restrict__ bsum) {
  const int b = blockIdx.x, t = threadIdx.x;
  const int base = b * SCAN_B;
  int v[4]; int tl = 0;
#pragma unroll
  for (int i = 0; i < 4; ++i) {
    const int idx = base + t * 4 + i;
    int c = 0;
    if (idx < NN) {
      c = cnt_in[idx] + cnt_in[NN + idx] + cnt_in[2 * NN + idx] + cnt_in[3 * NN + idx];
    }
    v[i] = c;
    tl += c;
  }
  __shared__ int sm[256];
  sm[t] = tl;
  __syncthreads();
  for (int off = 1; off < 256; off <<= 1) {
    const int x = (t >= off) ? sm[t - off] : 0;
    __syncthreads();
    sm[t] += x;
    __syncthreads();
  }
  const int incl = sm[t];
  int run = incl - tl;
#pragma unroll
  for (int i = 0; i < 4; ++i) {
    const int idx = base + t * 4 + i;
    if (idx < NN) excl[idx] = run;
    run += v[i];
  }
  if (t == 255) bsum[b] = incl;
}

__global__ __launch_bounds__(128) void scan2_k(int* __restrict__ bsum, int nb) {
  const int t = threadIdx.x;
  __shared__ int sm[128];
  const int v = (t < nb) ? bsum[t] : 0;
  sm[t] = v;
  __syncthreads();
  for (int off = 1; off < 128; off <<= 1) {
    const int x = (t >= off) ? sm[t - off] : 0;
    __syncthreads();
    sm[t] += x;
    __syncthreads();
  }
  if (t < nb) bsum[t] = sm[t] - v;
}

__global__ __launch_bounds__(256) void scan3_k(const int* __restrict__ excl,
                                               const int* __restrict__ bsum,
                                               int* __restrict__ row_ptr,
                                               int* __restrict__ cursor) {
  const int i = blockIdx.x * 256 + threadIdx.x;
  if (i < NN) {
    const int v = excl[i] + bsum[i / SCAN_B];
    row_ptr[i] = v;
    cursor[i] = v;
  }
  if (i == 0) row_ptr[NN] = NR * NE;
}

// fill combined CSR: entry = (src<<2)|r   [CHANGED from R5: int payload, no stored weight]
__global__ __launch_bounds__(256) void fill_k(const int* __restrict__ edges,
                                              int* __restrict__ cursor,
                                              int* __restrict__ csr) {
  const int r = blockIdx.y;
  const int e = blockIdx.x * 256 + threadIdx.x;
  if (e >= NE) return;
  const int s = edges[(size_t)r * 2 * NE + e];
  const int d = edges[(size_t)r * 2 * NE + NE + e];
  const int pos = atomicAdd(&cursor[d], 1);
  csr[pos] = (s << 2) | r;
}

// summed biases (R5 verbatim)
__global__ __launch_bounds__(128) void bias_sum_k(const float* __restrict__ b1,
                                                  const float* __restrict__ b2,
                                                  float* __restrict__ bs1,
                                                  float* __restrict__ bs2) {
  const int t = threadIdx.x;
  bs1[t] = b1[t] + b1[128 + t] + b1[256 + t] + b1[384 + t];
  if (t < 64) bs2[t] = b2[t] + b2[64 + t] + b2[128 + t] + b2[192 + t];
}

// ---------------------------------------------------------------- converts (R5 verbatim)
__global__ __launch_bounds__(256) void cvtx_k(const float* __restrict__ x,
                                              unsigned short* __restrict__ xb, int n8) {
  const int i = blockIdx.x * 256 + threadIdx.x;
  if (i >= n8) return;
  const float4 a = *(const float4*)&x[i * 8];
  const float4 b = *(const float4*)&x[i * 8 + 4];
  unsigned short o[8];
  o[0] = f2bf(a.x); o[1] = f2bf(a.y); o[2] = f2bf(a.z); o[3] = f2bf(a.w);
  o[4] = f2bf(b.x); o[5] = f2bf(b.y); o[6] = f2bf(b.z); o[7] = f2bf(b.w);
  *(bf16x8*)&xb[i * 8] = *(bf16x8*)o;
}

// W [r][k=128][N] f32 -> Wt [r][N][k=128] bf16 (R5 verbatim)
__global__ __launch_bounds__(256) void cvtw_k(const float* __restrict__ W,
                                              unsigned short* __restrict__ Wt,
                                              int N, int total) {
  const int i = blockIdx.x * 256 + threadIdx.x;
  if (i >= total) return;
  const int r = i / (128 * N);
  const int k = (i / N) % 128;
  const int n = i % N;
  Wt[((size_t)r * N + n) * 128 + k] = f2bf(W[i]);
}

// ---------------------------------------------------------------- MFMA GEMM (R5 verbatim)
template <int NOUT>
__global__ __launch_bounds__(256, 2) void gemm2_k(const unsigned short* __restrict__ Xb,
                                                  const unsigned short* __restrict__ Wt,
                                                  const float* __restrict__ rs,
                                                  unsigned short* __restrict__ H,
                                                  int M, int ntiles) {
  __shared__ unsigned short Xl[2][128 * 128];  // 2 x 32KB

  const int z = blockIdx.z;
  const unsigned short* Wtr = Wt + (size_t)z * NOUT * 128;
  const float* rsr = rs + (size_t)z * NN;
  unsigned short* Hr = H + (size_t)z * NN * NOUT;

  const int t = threadIdx.x;
  const int wid = t >> 6;
  const int lane = t & 63;
  const int lg = lane >> 4;
  const int lr = lane & 15;

  constexpr int MF = (NOUT == 128) ? 4 : 2;
  constexpr int NF = 4;
  const int rowg = (NOUT == 128) ? (wid & 1) : wid;
  const int colg = (NOUT == 128) ? (wid >> 1) : 0;
  const int rbase = rowg * MF * 16;
  const int cbase = colg * 64;

  bf16x8 bw[NF][4];
#pragma unroll
  for (int nf = 0; nf < NF; ++nf)
#pragma unroll
    for (int ks = 0; ks < 4; ++ks)
      bw[nf][ks] = *(const bf16x8*)&Wtr[(size_t)(cbase + nf * 16 + lr) * 128 + ks * 32 + lg * 8];

  auto stage = [&](int buf, int tile) {
    const int row0 = tile * 128;
#pragma unroll
    for (int i = 0; i < 8; ++i) {
      const int rl = wid * 32 + i * 4 + (lane >> 4);
      int gr = row0 + rl;
      if (gr >= M) gr = M - 1;
      const int q = (lane & 15) ^ (rl & 7);
      gll16(&Xb[(size_t)gr * 128 + q * 8], &Xl[buf][rl * 128 + (lane & 15) * 8]);
    }
  };

  int tile = blockIdx.x;
  if (tile >= ntiles) return;
  stage(0, tile);
  __syncthreads();
  int buf = 0;

  for (; tile < ntiles; tile += gridDim.x) {
    const int nxt = tile + gridDim.x;
    if (nxt < ntiles) stage(buf ^ 1, nxt);

    f32x4 acc[MF][NF];
#pragma unroll
    for (int mf = 0; mf < MF; ++mf)
#pragma unroll
      for (int nf = 0; nf < NF; ++nf) acc[mf][nf] = (f32x4){0.f, 0.f, 0.f, 0.f};

#pragma unroll
    for (int ks = 0; ks < 4; ++ks) {
#pragma unroll
      for (int mf = 0; mf < MF; ++mf) {
        const int r = rbase + mf * 16 + lr;
        const bf16x8 a =
            *(const bf16x8*)&Xl[buf][r * 128 + (((ks * 4 + lg) ^ (lr & 7)) << 3)];
#pragma unroll
        for (int nf = 0; nf < NF; ++nf)
          acc[mf][nf] = __builtin_amdgcn_mfma_f32_16x16x32_bf16(a, bw[nf][ks], acc[mf][nf], 0, 0, 0);
      }
    }

    const int row0 = tile * 128;
#pragma unroll
    for (int mf = 0; mf < MF; ++mf) {
#pragma unroll
      for (int i = 0; i < 4; ++i) {
        const int row = row0 + rbase + mf * 16 + lg * 4 + i;
        if (row < M) {
          const float s = rsr[row];
#pragma unroll
          for (int nf = 0; nf < NF; ++nf)
            Hr[(size_t)row * NOUT + cbase + nf * 16 + lr] = f2bf(acc[mf][nf][i] * s);
        }
      }
    }
    __syncthreads();
    buf ^= 1;
  }
}

// ---------------------------------------------------------------- gathers (R5 geometry; int entries, w from rs_in array)
// gather1: F=128, 4 groups x 16 lanes
__global__ __launch_bounds__(256) void gather1_k(const unsigned short* __restrict__ H,
                                                 const int* __restrict__ row_ptr,
                                                 const int* __restrict__ csr,
                                                 const float* __restrict__ rsin,
                                                 const float* __restrict__ bs1,
                                                 unsigned short* __restrict__ h1b) {
  const int node = blockIdx.x * 4 + (threadIdx.x >> 6);
  const int lane = threadIdx.x & 63;
  if (node >= NN) return;
  const int g  = lane >> 4;   // edge slot 0..3
  const int fl = lane & 15;   // feature chunk (8 bf16)

  // proven per-(r,node) weights from the rs_in array
  const float w0 = rsin[node];
  const float w1 = rsin[(size_t)NN + node];
  const float w2 = rsin[(size_t)2 * NN + node];
  const float w3 = rsin[(size_t)3 * NN + node];

  float acc[8];
#pragma unroll
  for (int j = 0; j < 8; ++j) acc[j] = 0.f;

  const int beg = row_ptr[node];
  const int end = row_ptr[node + 1];
  for (int e = beg + g; e < end; e += 4) {
    const int ee = csr[e];
    const int rE = ee & 3;
    const int row = rE * NN + (ee >> 2);
    const float w = (rE == 0) ? w0 : (rE == 1) ? w1 : (rE == 2) ? w2 : w3;
    const bf16x8 h = *(const bf16x8*)&H[(size_t)row * 128 + fl * 8];
#pragma unroll
    for (int j = 0; j < 8; ++j)
      acc[j] = fmaf(bf2f((unsigned short)h[j]), w, acc[j]);
  }
  // combine the 4 edge-groups (same features, different edges)
#pragma unroll
  for (int j = 0; j < 8; ++j) {
    acc[j] += __shfl_xor(acc[j], 16);
    acc[j] += __shfl_xor(acc[j], 32);
  }
  if (g == 0) {
    const float4 c0 = *(const float4*)&bs1[fl * 8];
    const float4 c1 = *(const float4*)&bs1[fl * 8 + 4];
    unsigned short o[8];
    o[0] = f2bf(fmaxf(acc[0] + c0.x, 0.f));
    o[1] = f2bf(fmaxf(acc[1] + c0.y, 0.f));
    o[2] = f2bf(fmaxf(acc[2] + c0.z, 0.f));
    o[3] = f2bf(fmaxf(acc[3] + c0.w, 0.f));
    o[4] = f2bf(fmaxf(acc[4] + c1.x, 0.f));
    o[5] = f2bf(fmaxf(acc[5] + c1.y, 0.f));
    o[6] = f2bf(fmaxf(acc[6] + c1.z, 0.f));
    o[7] = f2bf(fmaxf(acc[7] + c1.w, 0.f));
    *(bf16x8*)&h1b[(size_t)node * 128 + fl * 8] = *(bf16x8*)o;
  }
}

// gather2: F=64, 8 groups x 8 lanes, f32 output
__global__ __launch_bounds__(256) void gather2_k(const unsigned short* __restrict__ H,
                                                 const int* __restrict__ row_ptr,
                                                 const int* __restrict__ csr,
                                                 const float* __restrict__ rsin,
                                                 const float* __restrict__ bs2,
                                                 float* __restrict__ out) {
  const int node = blockIdx.x * 4 + (threadIdx.x >> 6);
  const int lane = threadIdx.x & 63;
  if (node >= NN) return;
  const int g  = lane >> 3;   // edge slot 0..7
  const int fl = lane & 7;    // feature chunk (8 bf16)

  const float w0 = rsin[node];
  const float w1 = rsin[(size_t)NN + node];
  const float w2 = rsin[(size_t)2 * NN + node];
  const float w3 = rsin[(size_t)3 * NN + node];

  float acc[8];
#pragma unroll
  for (int j = 0; j < 8; ++j) acc[j] = 0.f;

  const int beg = row_ptr[node];
  const int end = row_ptr[node + 1];
  for (int e = beg + g; e < end; e += 8) {
    const int ee = csr[e];
    const int rE = ee & 3;
    const int row = rE * NN + (ee >> 2);
    const float w = (rE == 0) ? w0 : (rE == 1) ? w1 : (rE == 2) ? w2 : w3;
    const bf16x8 h = *(const bf16x8*)&H[(size_t)row * 64 + fl * 8];
#pragma unroll
    for (int j = 0; j < 8; ++j)
      acc[j] = fmaf(bf2f((unsigned short)h[j]), w, acc[j]);
  }
#pragma unroll
  for (int j = 0; j < 8; ++j) {
    acc[j] += __shfl_xor(acc[j], 8);
    acc[j] += __shfl_xor(acc[j], 16);
    acc[j] += __shfl_xor(acc[j], 32);
  }
  if (g == 0) {
    const float4 c0 = *(const float4*)&bs2[fl * 8];
    const float4 c1 = *(const float4*)&bs2[fl * 8 + 4];
    float4 o0, o1;
    o0.x = acc[0] + c0.x; o0.y = acc[1] + c0.y; o0.z = acc[2] + c0.z; o0.w = acc[3] + c0.w;
    o1.x = acc[4] + c1.x; o1.y = acc[5] + c1.y; o1.z = acc[6] + c1.z; o1.w = acc[7] + c1.w;
    *(float4*)&out[(size_t)node * 64 + fl * 8]     = o0;
    *(float4*)&out[(size_t)node * 64 + fl * 8 + 4] = o1;
  }
}

// ---------------------------------------------------------------- launch
extern "C" void kernel_launch(void* const* d_in, const int* in_sizes, int n_in,
                              void* d_out, int out_size, void* d_ws, size_t ws_size,
                              hipStream_t stream) {
  const float* x     = (const float*)d_in[0];
  const int*   edges = (const int*)d_in[1];
  const float* W1    = (const float*)d_in[2];
  const float* b1    = (const float*)d_in[3];
  const float* W2    = (const float*)d_in[4];
  const float* b2    = (const float*)d_in[5];
  float* out = (float*)d_out;

  // ---- workspace layout (R5 verbatim; csr now int, smaller)
  unsigned short* xb   = (unsigned short*)d_ws;            // NN*128 bf16
  unsigned short* h1b  = xb;                               // reuse after layer1 GEMM
  unsigned short* Hbuf = xb + (size_t)NN * 128;            // NR*NN*128 bf16
  unsigned short* Wt1  = Hbuf + (size_t)NR * NN * 128;     // NR*128*128 bf16
  unsigned short* Wt2  = Wt1 + (size_t)NR * 128 * 128;     // NR*64*128 bf16
  float* rs_out = (float*)(Wt2 + (size_t)NR * 64 * 128);   // NR*NN
  float* rs_in  = rs_out + (size_t)NR * NN;                // NR*NN
  int* cnt_out  = (int*)(rs_in + (size_t)NR * NN);         // NR*NN
  int* cnt_in   = cnt_out + (size_t)NR * NN;               // NR*NN
  int* row_ptr  = cnt_in + (size_t)NR * NN;                // NN+1
  int* cursor   = row_ptr + (NN + 1);                      // NN
  int* bsum     = cursor + NN;                             // 128
  float* bs1    = (float*)(bsum + 128);                    // 128
  float* bs2    = bs1 + 128;                               // 64
  int* csr      = (int*)(bs2 + 64);                        // NR*NE int

  const int nb = (NN + SCAN_B - 1) / SCAN_B;  // 98

  // ---- degrees + combined CSR (R5 verbatim)
  hipMemsetAsync(cnt_out, 0, (size_t)2 * NR * NN * sizeof(int), stream);
  count_k<<<dim3((NE + 255) / 256, NR), 256, 0, stream>>>(edges, cnt_out, cnt_in);
  rs_k<<<(2 * NR * NN + 255) / 256, 256, 0, stream>>>(cnt_out, rs_out, 2 * NR * NN);
  scan1_k<<<nb, 256, 0, stream>>>(cnt_in, cursor /*excl temp*/, bsum);
  scan2_k<<<1, 128, 0, stream>>>(bsum, nb);
  scan3_k<<<(NN + 255) / 256, 256, 0, stream>>>(cursor, bsum, row_ptr, cursor);
  fill_k<<<dim3((NE + 255) / 256, NR), 256, 0, stream>>>(edges, cursor, csr);
  bias_sum_k<<<1, 128, 0, stream>>>(b1, b2, bs1, bs2);

  // ---- bf16 conversions (R5 verbatim)
  cvtx_k<<<((NN * 128 / 8) + 255) / 256, 256, 0, stream>>>(x, xb, NN * 128 / 8);
  cvtw_k<<<(NR * 128 * 128 + 255) / 256, 256, 0, stream>>>(W1, Wt1, 128, NR * 128 * 128);
  cvtw_k<<<(NR * 128 * 64 + 255) / 256, 256, 0, stream>>>(W2, Wt2, 64, NR * 128 * 64);

  const int ntiles = (NN + 127) / 128;  // 782

  // ---- layer 1
  gemm2_k<128><<<dim3(128, 1, NR), 256, 0, stream>>>(xb, Wt1, rs_out, Hbuf, NN, ntiles);
  gather1_k<<<(NN + 3) / 4, 256, 0, stream>>>(Hbuf, row_ptr, csr, rs_in, bs1, h1b);

  // ---- layer 2
  gemm2_k<64><<<dim3(128, 1, NR), 256, 0, stream>>>(h1b, Wt2, rs_out, Hbuf, NN, ntiles);
  gather2_k<<<(NN + 3) / 4, 256, 0, stream>>>(Hbuf, row_ptr, csr, rs_in, bs2, out);
}

// Round 9
// 252.241 us; speedup vs baseline: 1.1087x; 1.1087x over previous
//
#include <hip/hip_runtime.h>
#include <cstddef>
#include <cstdint>

#define NN   100000   // nodes
#define NR   4        // relations
#define NE   160000   // edges per relation
#define SCAN_B 1024

typedef short bf16x8 __attribute__((ext_vector_type(8)));
typedef float f32x4  __attribute__((ext_vector_type(4)));

__device__ __forceinline__ unsigned short f2bf(float f) {  // RNE f32->bf16
  union { float f; unsigned u; } v; v.f = f;
  unsigned r = v.u + 0x7fffu + ((v.u >> 16) & 1u);
  return (unsigned short)(r >> 16);
}
__device__ __forceinline__ float bf2f(unsigned short h) {
  union { unsigned u; float f; } v; v.u = ((unsigned)h) << 16;
  return v.f;
}

// async global->LDS, 16B per lane, linear LDS dest
__device__ __forceinline__ void gll16(const unsigned short* g, unsigned short* l) {
  __builtin_amdgcn_global_load_lds(
      (const __attribute__((address_space(1))) void*)g,
      (__attribute__((address_space(3))) void*)l, 16, 0, 0);
}

// ---------------------------------------------------------------- phase 1 (merged)
// blocks [0,2500): count  | [2500,8750): cvtx | [8750,9006): cvtw1
// [9006,9134): cvtw2      | [9134]: bias_sum
#define P1_NBLK 9135
__global__ __launch_bounds__(256) void phase1_k(const int* __restrict__ edges,
                                                const float* __restrict__ x,
                                                const float* __restrict__ W1,
                                                const float* __restrict__ W2,
                                                const float* __restrict__ b1,
                                                const float* __restrict__ b2,
                                                int* __restrict__ cnt_out,
                                                int* __restrict__ cnt_in,
                                                unsigned short* __restrict__ xb,
                                                unsigned short* __restrict__ Wt1,
                                                unsigned short* __restrict__ Wt2,
                                                float* __restrict__ bs1,
                                                float* __restrict__ bs2) {
  const int bid = blockIdx.x;
  const int t = threadIdx.x;
  if (bid < 2500) {  // count: 625 blocks per relation, 625*256 == NE exactly
    const int r = bid / 625;
    const int e = (bid - r * 625) * 256 + t;
    const int s = edges[(size_t)r * 2 * NE + e];
    const int d = edges[(size_t)r * 2 * NE + NE + e];
    atomicAdd(&cnt_out[(size_t)r * NN + s], 1);
    atomicAdd(&cnt_in[(size_t)r * NN + d], 1);
  } else if (bid < 8750) {  // cvtx: 6250 blocks, 6250*256 == NN*128/8 exactly
    const int i = (bid - 2500) * 256 + t;
    const float4 a = *(const float4*)&x[(size_t)i * 8];
    const float4 b = *(const float4*)&x[(size_t)i * 8 + 4];
    unsigned short o[8];
    o[0] = f2bf(a.x); o[1] = f2bf(a.y); o[2] = f2bf(a.z); o[3] = f2bf(a.w);
    o[4] = f2bf(b.x); o[5] = f2bf(b.y); o[6] = f2bf(b.z); o[7] = f2bf(b.w);
    *(bf16x8*)&xb[(size_t)i * 8] = *(bf16x8*)o;
  } else if (bid < 9006) {  // cvtw1: 256 blocks, 65536 == NR*128*128
    const int i = (bid - 8750) * 256 + t;
    const int r = i / (128 * 128);
    const int k = (i / 128) % 128;
    const int n = i % 128;
    Wt1[((size_t)r * 128 + n) * 128 + k] = f2bf(W1[i]);
  } else if (bid < 9134) {  // cvtw2: 128 blocks, 32768 == NR*128*64
    const int i = (bid - 9006) * 256 + t;
    const int r = i / (128 * 64);
    const int k = (i / 64) % 128;
    const int n = i % 64;
    Wt2[((size_t)r * 64 + n) * 128 + k] = f2bf(W2[i]);
  } else {  // bias sums
    if (t < 128) bs1[t] = b1[t] + b1[128 + t] + b1[256 + t] + b1[384 + t];
    if (t < 64)  bs2[t] = b2[t] + b2[64 + t] + b2[128 + t] + b2[192 + t];
  }
}

// ---------------------------------------------------------------- scans (R5 verbatim)
__global__ __launch_bounds__(256) void scan1_k(const int* __restrict__ cnt_in,
                                               int* __restrict__ excl,
                                               int* __restrict__ bsum) {
  const int b = blockIdx.x, t = threadIdx.x;
  const int base = b * SCAN_B;
  int v[4]; int tl = 0;
#pragma unroll
  for (int i = 0; i < 4; ++i) {
    const int idx = base + t * 4 + i;
    int c = 0;
    if (idx < NN) {
      c = cnt_in[idx] + cnt_in[NN + idx] + cnt_in[2 * NN + idx] + cnt_in[3 * NN + idx];
    }
    v[i] = c;
    tl += c;
  }
  __shared__ int sm[256];
  sm[t] = tl;
  __syncthreads();
  for (int off = 1; off < 256; off <<= 1) {
    const int x = (t >= off) ? sm[t - off] : 0;
    __syncthreads();
    sm[t] += x;
    __syncthreads();
  }
  const int incl = sm[t];
  int run = incl - tl;
#pragma unroll
  for (int i = 0; i < 4; ++i) {
    const int idx = base + t * 4 + i;
    if (idx < NN) excl[idx] = run;
    run += v[i];
  }
  if (t == 255) bsum[b] = incl;
}

__global__ __launch_bounds__(128) void scan2_k(int* __restrict__ bsum, int nb) {
  const int t = threadIdx.x;
  __shared__ int sm[128];
  const int v = (t < nb) ? bsum[t] : 0;
  sm[t] = v;
  __syncthreads();
  for (int off = 1; off < 128; off <<= 1) {
    const int x = (t >= off) ? sm[t - off] : 0;
    __syncthreads();
    sm[t] += x;
    __syncthreads();
  }
  if (t < nb) bsum[t] = sm[t] - v;
}

// scan3 + rs merged: blocks [0,3125): rs over 2*NR*NN (==3125*256); [3125,3516): scan3
__global__ __launch_bounds__(256) void scan3rs_k(const int* __restrict__ cnt,
                                                 float* __restrict__ rs,
                                                 const int* __restrict__ bsum,
                                                 int* __restrict__ row_ptr,
                                                 int* __restrict__ cursor) {
  const int bid = blockIdx.x, t = threadIdx.x;
  if (bid < 3125) {
    const int i = bid * 256 + t;
    rs[i] = rsqrtf(fmaxf((float)cnt[i], 1.0f));
  } else {
    const int i = (bid - 3125) * 256 + t;
    if (i < NN) {
      const int v = cursor[i] + bsum[i / SCAN_B];  // cursor holds excl from scan1
      row_ptr[i] = v;
      cursor[i] = v;
    }
    if (i == 0) row_ptr[NN] = NR * NE;
  }
}

// ---------------------------------------------------------------- MFMA GEMM (+optional fused fill)
// z in [0,NR): gemm for relation z (R5-verbatim compute path).
// DOFILL && z==NR: grid-stride CSR fill (R5 semantics: int2 payload (r*NN+src, bits(rs_in[r][d]))).
template <int NOUT, bool DOFILL>
__global__ __launch_bounds__(256, 2) void gemm2_k(const unsigned short* __restrict__ Xb,
                                                  const unsigned short* __restrict__ Wt,
                                                  const float* __restrict__ rs,
                                                  unsigned short* __restrict__ H,
                                                  int M, int ntiles,
                                                  const int* __restrict__ edges,
                                                  const float* __restrict__ rsin,
                                                  int* __restrict__ cursor,
                                                  int2* __restrict__ csr) {
  __shared__ unsigned short Xl[2][128 * 128];  // 2 x 32KB

  if (DOFILL && blockIdx.z == NR) {
    const int stride = gridDim.x * 256;
    for (int i = blockIdx.x * 256 + threadIdx.x; i < NR * NE; i += stride) {
      const int r = i / NE;
      const int e = i - r * NE;
      const int s = edges[(size_t)r * 2 * NE + e];
      const int d = edges[(size_t)r * 2 * NE + NE + e];
      const int pos = atomicAdd(&cursor[d], 1);
      csr[pos] = make_int2(r * NN + s, __float_as_int(rsin[(size_t)r * NN + d]));
    }
    return;
  }

  const int z = blockIdx.z;
  const unsigned short* Wtr = Wt + (size_t)z * NOUT * 128;
  const float* rsr = rs + (size_t)z * NN;
  unsigned short* Hr = H + (size_t)z * NN * NOUT;

  const int t = threadIdx.x;
  const int wid = t >> 6;
  const int lane = t & 63;
  const int lg = lane >> 4;
  const int lr = lane & 15;

  constexpr int MF = (NOUT == 128) ? 4 : 2;
  constexpr int NF = 4;
  const int rowg = (NOUT == 128) ? (wid & 1) : wid;
  const int colg = (NOUT == 128) ? (wid >> 1) : 0;
  const int rbase = rowg * MF * 16;
  const int cbase = colg * 64;

  bf16x8 bw[NF][4];
#pragma unroll
  for (int nf = 0; nf < NF; ++nf)
#pragma unroll
    for (int ks = 0; ks < 4; ++ks)
      bw[nf][ks] = *(const bf16x8*)&Wtr[(size_t)(cbase + nf * 16 + lr) * 128 + ks * 32 + lg * 8];

  auto stage = [&](int buf, int tile) {
    const int row0 = tile * 128;
#pragma unroll
    for (int i = 0; i < 8; ++i) {
      const int rl = wid * 32 + i * 4 + (lane >> 4);
      int gr = row0 + rl;
      if (gr >= M) gr = M - 1;
      const int q = (lane & 15) ^ (rl & 7);
      gll16(&Xb[(size_t)gr * 128 + q * 8], &Xl[buf][rl * 128 + (lane & 15) * 8]);
    }
  };

  int tile = blockIdx.x;
  if (tile >= ntiles) return;
  stage(0, tile);
  __syncthreads();
  int buf = 0;

  for (; tile < ntiles; tile += gridDim.x) {
    const int nxt = tile + gridDim.x;
    if (nxt < ntiles) stage(buf ^ 1, nxt);

    f32x4 acc[MF][NF];
#pragma unroll
    for (int mf = 0; mf < MF; ++mf)
#pragma unroll
      for (int nf = 0; nf < NF; ++nf) acc[mf][nf] = (f32x4){0.f, 0.f, 0.f, 0.f};

#pragma unroll
    for (int ks = 0; ks < 4; ++ks) {
#pragma unroll
      for (int mf = 0; mf < MF; ++mf) {
        const int r = rbase + mf * 16 + lr;
        const bf16x8 a =
            *(const bf16x8*)&Xl[buf][r * 128 + (((ks * 4 + lg) ^ (lr & 7)) << 3)];
#pragma unroll
        for (int nf = 0; nf < NF; ++nf)
          acc[mf][nf] = __builtin_amdgcn_mfma_f32_16x16x32_bf16(a, bw[nf][ks], acc[mf][nf], 0, 0, 0);
      }
    }

    const int row0 = tile * 128;
#pragma unroll
    for (int mf = 0; mf < MF; ++mf) {
#pragma unroll
      for (int i = 0; i < 4; ++i) {
        const int row = row0 + rbase + mf * 16 + lg * 4 + i;
        if (row < M) {
          const float s = rsr[row];
#pragma unroll
          for (int nf = 0; nf < NF; ++nf)
            Hr[(size_t)row * NOUT + cbase + nf * 16 + lr] = f2bf(acc[mf][nf][i] * s);
        }
      }
    }
    __syncthreads();
    buf ^= 1;
  }
}

// ---------------------------------------------------------------- gathers (R5 verbatim, int2 csr)
// gather1: F=128, 4 edge-groups x 16 lanes, bf16 out + bias + relu
__global__ __launch_bounds__(256) void gather1_k(const unsigned short* __restrict__ H,
                                                 const int* __restrict__ row_ptr,
                                                 const int2* __restrict__ csr,
                                                 const float* __restrict__ bs1,
                                                 unsigned short* __restrict__ h1b) {
  const int node = blockIdx.x * 4 + (threadIdx.x >> 6);
  const int lane = threadIdx.x & 63;
  if (node >= NN) return;
  const int g  = lane >> 4;
  const int fl = lane & 15;

  float acc[8];
#pragma unroll
  for (int j = 0; j < 8; ++j) acc[j] = 0.f;

  const int beg = row_ptr[node];
  const int end = row_ptr[node + 1];
  for (int e = beg + g; e < end; e += 4) {
    const int2 p = csr[e];
    const float w = __int_as_float(p.y);
    const bf16x8 h = *(const bf16x8*)&H[(size_t)p.x * 128 + fl * 8];
#pragma unroll
    for (int j = 0; j < 8; ++j)
      acc[j] = fmaf(bf2f((unsigned short)h[j]), w, acc[j]);
  }
#pragma unroll
  for (int j = 0; j < 8; ++j) {
    acc[j] += __shfl_xor(acc[j], 16);
    acc[j] += __shfl_xor(acc[j], 32);
  }
  if (g == 0) {
    const float4 c0 = *(const float4*)&bs1[fl * 8];
    const float4 c1 = *(const float4*)&bs1[fl * 8 + 4];
    unsigned short o[8];
    o[0] = f2bf(fmaxf(acc[0] + c0.x, 0.f));
    o[1] = f2bf(fmaxf(acc[1] + c0.y, 0.f));
    o[2] = f2bf(fmaxf(acc[2] + c0.z, 0.f));
    o[3] = f2bf(fmaxf(acc[3] + c0.w, 0.f));
    o[4] = f2bf(fmaxf(acc[4] + c1.x, 0.f));
    o[5] = f2bf(fmaxf(acc[5] + c1.y, 0.f));
    o[6] = f2bf(fmaxf(acc[6] + c1.z, 0.f));
    o[7] = f2bf(fmaxf(acc[7] + c1.w, 0.f));
    *(bf16x8*)&h1b[(size_t)node * 128 + fl * 8] = *(bf16x8*)o;
  }
}

// gather2: F=64, 8 edge-groups x 8 lanes, f32 out + bias
__global__ __launch_bounds__(256) void gather2_k(const unsigned short* __restrict__ H,
                                                 const int* __restrict__ row_ptr,
                                                 const int2* __restrict__ csr,
                                                 const float* __restrict__ bs2,
                                                 float* __restrict__ out) {
  const int node = blockIdx.x * 4 + (threadIdx.x >> 6);
  const int lane = threadIdx.x & 63;
  if (node >= NN) return;
  const int g  = lane >> 3;
  const int fl = lane & 7;

  float acc[8];
#pragma unroll
  for (int j = 0; j < 8; ++j) acc[j] = 0.f;

  const int beg = row_ptr[node];
  const int end = row_ptr[node + 1];
  for (int e = beg + g; e < end; e += 8) {
    const int2 p = csr[e];
    const float w = __int_as_float(p.y);
    const bf16x8 h = *(const bf16x8*)&H[(size_t)p.x * 64 + fl * 8];
#pragma unroll
    for (int j = 0; j < 8; ++j)
      acc[j] = fmaf(bf2f((unsigned short)h[j]), w, acc[j]);
  }
#pragma unroll
  for (int j = 0; j < 8; ++j) {
    acc[j] += __shfl_xor(acc[j], 8);
    acc[j] += __shfl_xor(acc[j], 16);
    acc[j] += __shfl_xor(acc[j], 32);
  }
  if (g == 0) {
    const float4 c0 = *(const float4*)&bs2[fl * 8];
    const float4 c1 = *(const float4*)&bs2[fl * 8 + 4];
    float4 o0, o1;
    o0.x = acc[0] + c0.x; o0.y = acc[1] + c0.y; o0.z = acc[2] + c0.z; o0.w = acc[3] + c0.w;
    o1.x = acc[4] + c1.x; o1.y = acc[5] + c1.y; o1.z = acc[6] + c1.z; o1.w = acc[7] + c1.w;
    *(float4*)&out[(size_t)node * 64 + fl * 8]     = o0;
    *(float4*)&out[(size_t)node * 64 + fl * 8 + 4] = o1;
  }
}

// ---------------------------------------------------------------- launch
extern "C" void kernel_launch(void* const* d_in, const int* in_sizes, int n_in,
                              void* d_out, int out_size, void* d_ws, size_t ws_size,
                              hipStream_t stream) {
  const float* x     = (const float*)d_in[0];
  const int*   edges = (const int*)d_in[1];
  const float* W1    = (const float*)d_in[2];
  const float* b1    = (const float*)d_in[3];
  const float* W2    = (const float*)d_in[4];
  const float* b2    = (const float*)d_in[5];
  float* out = (float*)d_out;

  // ---- workspace layout (R5 verbatim)
  unsigned short* xb   = (unsigned short*)d_ws;            // NN*128 bf16
  unsigned short* h1b  = xb;                               // reuse after layer1 GEMM
  unsigned short* Hbuf = xb + (size_t)NN * 128;            // NR*NN*128 bf16
  unsigned short* Wt1  = Hbuf + (size_t)NR * NN * 128;     // NR*128*128 bf16
  unsigned short* Wt2  = Wt1 + (size_t)NR * 128 * 128;     // NR*64*128 bf16
  float* rs_out = (float*)(Wt2 + (size_t)NR * 64 * 128);   // NR*NN
  float* rs_in  = rs_out + (size_t)NR * NN;                // NR*NN
  int* cnt_out  = (int*)(rs_in + (size_t)NR * NN);         // NR*NN
  int* cnt_in   = cnt_out + (size_t)NR * NN;               // NR*NN
  int* row_ptr  = cnt_in + (size_t)NR * NN;                // NN+1
  int* cursor   = row_ptr + (NN + 1);                      // NN
  int* bsum     = cursor + NN;                             // 128
  float* bs1    = (float*)(bsum + 128);                    // 128
  float* bs2    = bs1 + 128;                               // 64
  int2* csr     = (int2*)(bs2 + 64);                       // NR*NE int2

  const int nb = (NN + SCAN_B - 1) / SCAN_B;  // 98

  // 1) zero counters
  hipMemsetAsync(cnt_out, 0, (size_t)2 * NR * NN * sizeof(int), stream);
  // 2) merged: count + cvtx + cvtw1 + cvtw2 + bias_sum
  phase1_k<<<P1_NBLK, 256, 0, stream>>>(edges, x, W1, W2, b1, b2,
                                        cnt_out, cnt_in, xb, Wt1, Wt2, bs1, bs2);
  // 3-5) scans + rs
  scan1_k<<<nb, 256, 0, stream>>>(cnt_in, cursor /*excl temp*/, bsum);
  scan2_k<<<1, 128, 0, stream>>>(bsum, nb);
  scan3rs_k<<<3125 + (NN + 255) / 256, 256, 0, stream>>>(cnt_out, rs_out, bsum, row_ptr, cursor);

  const int ntiles = (NN + 127) / 128;  // 782

  // 6) layer-1 GEMM (z=0..3) with fused CSR fill (z=4); 500 blocks co-resident at 2/CU
  gemm2_k<128, true><<<dim3(100, 1, NR + 1), 256, 0, stream>>>(
      xb, Wt1, rs_out, Hbuf, NN, ntiles, edges, rs_in, cursor, csr);
  // 7) fused gather+bias+relu -> h1b
  gather1_k<<<(NN + 3) / 4, 256, 0, stream>>>(Hbuf, row_ptr, csr, bs1, h1b);

  // 8) layer-2 GEMM
  gemm2_k<64, false><<<dim3(128, 1, NR), 256, 0, stream>>>(
      h1b, Wt2, rs_out, Hbuf, NN, ntiles, nullptr, nullptr, nullptr, nullptr);
  // 9) fused gather+bias -> out
  gather2_k<<<(NN + 3) / 4, 256, 0, stream>>>(Hbuf, row_ptr, csr, bs2, out);
}

// Round 10
// 214.882 us; speedup vs baseline: 1.3014x; 1.1739x over previous
//
#include <hip/hip_runtime.h>
#include <cstddef>
#include <cstdint>

#define NN   100000   // nodes
#define NR   4        // relations
#define NE   160000   // edges per relation
#define SCAN_B 1024
#define GEMMB 512     // gemm virtual blocks in phaseB (128 per relation)

typedef short bf16x8 __attribute__((ext_vector_type(8)));
typedef float f32x4  __attribute__((ext_vector_type(4)));

__device__ __forceinline__ unsigned short f2bf(float f) {  // RNE f32->bf16
  union { float f; unsigned u; } v; v.f = f;
  unsigned r = v.u + 0x7fffu + ((v.u >> 16) & 1u);
  return (unsigned short)(r >> 16);
}
__device__ __forceinline__ float bf2f(unsigned short h) {
  union { unsigned u; float f; } v; v.u = ((unsigned)h) << 16;
  return v.f;
}

// async global->LDS, 16B per lane, linear LDS dest
__device__ __forceinline__ void gll16(const unsigned short* g, unsigned short* l) {
  __builtin_amdgcn_global_load_lds(
      (const __attribute__((address_space(1))) void*)g,
      (__attribute__((address_space(3))) void*)l, 16, 0, 0);
}

// ---------------------------------------------------------------- phase A (merged streaming prep)
// [0,782): zero cnt arrays (int4) | [782,7032): cvtx | [7032,7288): cvtw1
// [7288,7416): cvtw2 | [7416]: bias sums
#define A_ZERO 782
#define A_NBLK (A_ZERO + 6250 + 256 + 128 + 1)  // 7417
__global__ __launch_bounds__(256) void phaseA_k(const float* __restrict__ x,
                                                const float* __restrict__ W1,
                                                const float* __restrict__ W2,
                                                const float* __restrict__ b1,
                                                const float* __restrict__ b2,
                                                int* __restrict__ cnt,      // cnt_out|cnt_in, 2*NR*NN ints
                                                unsigned short* __restrict__ xb,
                                                unsigned short* __restrict__ Wt1,
                                                unsigned short* __restrict__ Wt2,
                                                float* __restrict__ bs1,
                                                float* __restrict__ bs2) {
  const int bid = blockIdx.x;
  const int t = threadIdx.x;
  if (bid < A_ZERO) {  // zero 800000 ints as int4
    const int i = bid * 256 + t;
    if (i < 2 * NR * NN / 4) ((int4*)cnt)[i] = make_int4(0, 0, 0, 0);
  } else if (bid < A_ZERO + 6250) {  // cvtx: 6250*256*8 == NN*128
    const int i = (bid - A_ZERO) * 256 + t;
    const float4 a = *(const float4*)&x[(size_t)i * 8];
    const float4 b = *(const float4*)&x[(size_t)i * 8 + 4];
    unsigned short o[8];
    o[0] = f2bf(a.x); o[1] = f2bf(a.y); o[2] = f2bf(a.z); o[3] = f2bf(a.w);
    o[4] = f2bf(b.x); o[5] = f2bf(b.y); o[6] = f2bf(b.z); o[7] = f2bf(b.w);
    *(bf16x8*)&xb[(size_t)i * 8] = *(bf16x8*)o;
  } else if (bid < A_ZERO + 6250 + 256) {  // cvtw1: 65536 == NR*128*128
    const int i = (bid - A_ZERO - 6250) * 256 + t;
    const int r = i / (128 * 128);
    const int k = (i / 128) % 128;
    const int n = i % 128;
    Wt1[((size_t)r * 128 + n) * 128 + k] = f2bf(W1[i]);
  } else if (bid < A_ZERO + 6250 + 256 + 128) {  // cvtw2: 32768 == NR*128*64
    const int i = (bid - A_ZERO - 6250 - 256) * 256 + t;
    const int r = i / (128 * 64);
    const int k = (i / 64) % 128;
    const int n = i % 64;
    Wt2[((size_t)r * 64 + n) * 128 + k] = f2bf(W2[i]);
  } else {
    if (t < 128) bs1[t] = b1[t] + b1[128 + t] + b1[256 + t] + b1[384 + t];
    if (t < 64)  bs2[t] = b2[t] + b2[64 + t] + b2[128 + t] + b2[192 + t];
  }
}

// ---------------------------------------------------------------- GEMM core (64-row tiles, UNSCALED)
// H[row][col] = bf16( sum_k Xb[row][k] * Wt[col][k] ), K=128. 4 waves: 2 row-groups x 2 col-groups.
// LDS: 2 x (64x128 bf16) = 32KB double buffer, XOR-swizzled via pre-swizzled global src.
template <int NOUT>
__device__ __forceinline__ void gemm_core(const unsigned short* __restrict__ Xb,
                                          const unsigned short* __restrict__ Wtr,
                                          unsigned short* __restrict__ Hr,
                                          int vb, unsigned short (*Xl)[64 * 128]) {
  const int t = threadIdx.x;
  const int wid = t >> 6;
  const int lane = t & 63;
  const int lg = lane >> 4;
  const int lr = lane & 15;

  constexpr int NF = (NOUT == 128) ? 4 : 2;    // col frags per wave
  const int rbase = (wid & 1) * 32;            // 2 row-groups x 32 rows
  const int cbase = (wid >> 1) * (NOUT / 2);   // 2 col-groups

  // preload W fragments (once; L2-hot)
  bf16x8 bw[NF][4];
#pragma unroll
  for (int nf = 0; nf < NF; ++nf)
#pragma unroll
    for (int ks = 0; ks < 4; ++ks)
      bw[nf][ks] = *(const bf16x8*)&Wtr[(size_t)(cbase + nf * 16 + lr) * 128 + ks * 32 + lg * 8];

  auto stage = [&](int buf, int tile) {
    const int row0 = tile * 64;
#pragma unroll
    for (int i = 0; i < 4; ++i) {
      const int rl = wid * 16 + i * 4 + (lane >> 4);
      int gr = row0 + rl;
      if (gr >= NN) gr = NN - 1;  // clamp; masked at store
      const int q = (lane & 15) ^ (rl & 7);
      gll16(&Xb[(size_t)gr * 128 + q * 8], &Xl[buf][rl * 128 + (lane & 15) * 8]);
    }
  };

  const int ntiles = (NN + 63) / 64;  // 1563
  int tile = vb;
  stage(0, tile);
  __syncthreads();
  int buf = 0;

  for (; tile < ntiles; tile += 128) {
    const int nxt = tile + 128;
    if (nxt < ntiles) stage(buf ^ 1, nxt);

    f32x4 acc[2][NF];
#pragma unroll
    for (int mf = 0; mf < 2; ++mf)
#pragma unroll
      for (int nf = 0; nf < NF; ++nf) acc[mf][nf] = (f32x4){0.f, 0.f, 0.f, 0.f};

#pragma unroll
    for (int ks = 0; ks < 4; ++ks) {
#pragma unroll
      for (int mf = 0; mf < 2; ++mf) {
        const int r = rbase + mf * 16 + lr;
        const bf16x8 a =
            *(const bf16x8*)&Xl[buf][r * 128 + (((ks * 4 + lg) ^ (lr & 7)) << 3)];
#pragma unroll
        for (int nf = 0; nf < NF; ++nf)
          acc[mf][nf] = __builtin_amdgcn_mfma_f32_16x16x32_bf16(a, bw[nf][ks], acc[mf][nf], 0, 0, 0);
      }
    }

    const int row0 = tile * 64;
#pragma unroll
    for (int mf = 0; mf < 2; ++mf) {
#pragma unroll
      for (int i = 0; i < 4; ++i) {
        const int row = row0 + rbase + mf * 16 + lg * 4 + i;
        if (row < NN) {
#pragma unroll
          for (int nf = 0; nf < NF; ++nf)
            Hr[(size_t)row * NOUT + cbase + nf * 16 + lr] = f2bf(acc[mf][nf][i]);
        }
      }
    }
    __syncthreads();
    buf ^= 1;
  }
}

// ---------------------------------------------------------------- phase B: gemm1 (unscaled) || count
// blocks [0,GEMMB): gemm z=bid>>7, virtual block bid&127
// blocks [GEMMB, GEMMB+2500): degree count atomics (625 blocks per relation)
__global__ __launch_bounds__(256, 2) void phaseB_k(const int* __restrict__ edges,
                                                   const unsigned short* __restrict__ xb,
                                                   const unsigned short* __restrict__ Wt1,
                                                   unsigned short* __restrict__ H,
                                                   int* __restrict__ cnt_out,
                                                   int* __restrict__ cnt_in) {
  __shared__ unsigned short Xl[2][64 * 128];  // 32 KB
  const int bid = blockIdx.x;
  if (bid < GEMMB) {
    const int z = bid >> 7;
    gemm_core<128>(xb, Wt1 + (size_t)z * 128 * 128, H + (size_t)z * NN * 128, bid & 127, Xl);
    return;
  }
  const int idx = bid - GEMMB;
  const int r = idx / 625;
  const int e = (idx - r * 625) * 256 + threadIdx.x;
  const int s = edges[(size_t)r * 2 * NE + e];
  const int d = edges[(size_t)r * 2 * NE + NE + e];
  atomicAdd(&cnt_out[(size_t)r * NN + s], 1);
  atomicAdd(&cnt_in[(size_t)r * NN + d], 1);
}

// standalone layer-2 GEMM (unscaled)
template <int NOUT>
__global__ __launch_bounds__(256, 2) void gemm3_k(const unsigned short* __restrict__ Xb,
                                                  const unsigned short* __restrict__ Wt,
                                                  unsigned short* __restrict__ H) {
  __shared__ unsigned short Xl[2][64 * 128];
  const int z = blockIdx.z;
  gemm_core<NOUT>(Xb, Wt + (size_t)z * NOUT * 128, H + (size_t)z * NN * NOUT, blockIdx.x, Xl);
}

// ---------------------------------------------------------------- scans (R9 verbatim)
__global__ __launch_bounds__(256) void scan1_k(const int* __restrict__ cnt_in,
                                               int* __restrict__ excl,
                                               int* __restrict__ bsum) {
  const int b = blockIdx.x, t = threadIdx.x;
  const int base = b * SCAN_B;
  int v[4]; int tl = 0;
#pragma unroll
  for (int i = 0; i < 4; ++i) {
    const int idx = base + t * 4 + i;
    int c = 0;
    if (idx < NN) {
      c = cnt_in[idx] + cnt_in[NN + idx] + cnt_in[2 * NN + idx] + cnt_in[3 * NN + idx];
    }
    v[i] = c;
    tl += c;
  }
  __shared__ int sm[256];
  sm[t] = tl;
  __syncthreads();
  for (int off = 1; off < 256; off <<= 1) {
    const int x = (t >= off) ? sm[t - off] : 0;
    __syncthreads();
    sm[t] += x;
    __syncthreads();
  }
  const int incl = sm[t];
  int run = incl - tl;
#pragma unroll
  for (int i = 0; i < 4; ++i) {
    const int idx = base + t * 4 + i;
    if (idx < NN) excl[idx] = run;
    run += v[i];
  }
  if (t == 255) bsum[b] = incl;
}

__global__ __launch_bounds__(128) void scan2_k(int* __restrict__ bsum, int nb) {
  const int t = threadIdx.x;
  __shared__ int sm[128];
  const int v = (t < nb) ? bsum[t] : 0;
  sm[t] = v;
  __syncthreads();
  for (int off = 1; off < 128; off <<= 1) {
    const int x = (t >= off) ? sm[t - off] : 0;
    __syncthreads();
    sm[t] += x;
    __syncthreads();
  }
  if (t < nb) bsum[t] = sm[t] - v;
}

// scan3 + rs merged: [0,3125): rs over 2*NR*NN; [3125,...): scan3
__global__ __launch_bounds__(256) void scan3rs_k(const int* __restrict__ cnt,
                                                 float* __restrict__ rs,
                                                 const int* __restrict__ bsum,
                                                 int* __restrict__ row_ptr,
                                                 int* __restrict__ cursor) {
  const int bid = blockIdx.x, t = threadIdx.x;
  if (bid < 3125) {
    const int i = bid * 256 + t;
    rs[i] = rsqrtf(fmaxf((float)cnt[i], 1.0f));
  } else {
    const int i = (bid - 3125) * 256 + t;
    if (i < NN) {
      const int v = cursor[i] + bsum[i / SCAN_B];  // cursor holds excl from scan1
      row_ptr[i] = v;
      cursor[i] = v;
    }
    if (i == 0) row_ptr[NN] = NR * NE;
  }
}

// ---------------------------------------------------------------- fill (combined edge weight)
// payload = (r*NN+src, bits( rs_in[r][d] * rs_out[r][s] ))
__global__ __launch_bounds__(256) void fill_k(const int* __restrict__ edges,
                                              const float* __restrict__ rs_out,
                                              const float* __restrict__ rs_in,
                                              int* __restrict__ cursor,
                                              int2* __restrict__ csr) {
  const int r = blockIdx.y;
  const int e = blockIdx.x * 256 + threadIdx.x;
  if (e >= NE) return;
  const int s = edges[(size_t)r * 2 * NE + e];
  const int d = edges[(size_t)r * 2 * NE + NE + e];
  const int pos = atomicAdd(&cursor[d], 1);
  const float w = rs_in[(size_t)r * NN + d] * rs_out[(size_t)r * NN + s];
  csr[pos] = make_int2(r * NN + s, __float_as_int(w));
}

// ---------------------------------------------------------------- gathers (R9 verbatim)
__global__ __launch_bounds__(256) void gather1_k(const unsigned short* __restrict__ H,
                                                 const int* __restrict__ row_ptr,
                                                 const int2* __restrict__ csr,
                                                 const float* __restrict__ bs1,
                                                 unsigned short* __restrict__ h1b) {
  const int node = blockIdx.x * 4 + (threadIdx.x >> 6);
  const int lane = threadIdx.x & 63;
  if (node >= NN) return;
  const int g  = lane >> 4;
  const int fl = lane & 15;

  float acc[8];
#pragma unroll
  for (int j = 0; j < 8; ++j) acc[j] = 0.f;

  const int beg = row_ptr[node];
  const int end = row_ptr[node + 1];
  for (int e = beg + g; e < end; e += 4) {
    const int2 p = csr[e];
    const float w = __int_as_float(p.y);
    const bf16x8 h = *(const bf16x8*)&H[(size_t)p.x * 128 + fl * 8];
#pragma unroll
    for (int j = 0; j < 8; ++j)
      acc[j] = fmaf(bf2f((unsigned short)h[j]), w, acc[j]);
  }
#pragma unroll
  for (int j = 0; j < 8; ++j) {
    acc[j] += __shfl_xor(acc[j], 16);
    acc[j] += __shfl_xor(acc[j], 32);
  }
  if (g == 0) {
    const float4 c0 = *(const float4*)&bs1[fl * 8];
    const float4 c1 = *(const float4*)&bs1[fl * 8 + 4];
    unsigned short o[8];
    o[0] = f2bf(fmaxf(acc[0] + c0.x, 0.f));
    o[1] = f2bf(fmaxf(acc[1] + c0.y, 0.f));
    o[2] = f2bf(fmaxf(acc[2] + c0.z, 0.f));
    o[3] = f2bf(fmaxf(acc[3] + c0.w, 0.f));
    o[4] = f2bf(fmaxf(acc[4] + c1.x, 0.f));
    o[5] = f2bf(fmaxf(acc[5] + c1.y, 0.f));
    o[6] = f2bf(fmaxf(acc[6] + c1.z, 0.f));
    o[7] = f2bf(fmaxf(acc[7] + c1.w, 0.f));
    *(bf16x8*)&h1b[(size_t)node * 128 + fl * 8] = *(bf16x8*)o;
  }
}

__global__ __launch_bounds__(256) void gather2_k(const unsigned short* __restrict__ H,
                                                 const int* __restrict__ row_ptr,
                                                 const int2* __restrict__ csr,
                                                 const float* __restrict__ bs2,
                                                 float* __restrict__ out) {
  const int node = blockIdx.x * 4 + (threadIdx.x >> 6);
  const int lane = threadIdx.x & 63;
  if (node >= NN) return;
  const int g  = lane >> 3;
  const int fl = lane & 7;

  float acc[8];
#pragma unroll
  for (int j = 0; j < 8; ++j) acc[j] = 0.f;

  const int beg = row_ptr[node];
  const int end = row_ptr[node + 1];
  for (int e = beg + g; e < end; e += 8) {
    const int2 p = csr[e];
    const float w = __int_as_float(p.y);
    const bf16x8 h = *(const bf16x8*)&H[(size_t)p.x * 64 + fl * 8];
#pragma unroll
    for (int j = 0; j < 8; ++j)
      acc[j] = fmaf(bf2f((unsigned short)h[j]), w, acc[j]);
  }
#pragma unroll
  for (int j = 0; j < 8; ++j) {
    acc[j] += __shfl_xor(acc[j], 8);
    acc[j] += __shfl_xor(acc[j], 16);
    acc[j] += __shfl_xor(acc[j], 32);
  }
  if (g == 0) {
    const float4 c0 = *(const float4*)&bs2[fl * 8];
    const float4 c1 = *(const float4*)&bs2[fl * 8 + 4];
    float4 o0, o1;
    o0.x = acc[0] + c0.x; o0.y = acc[1] + c0.y; o0.z = acc[2] + c0.z; o0.w = acc[3] + c0.w;
    o1.x = acc[4] + c1.x; o1.y = acc[5] + c1.y; o1.z = acc[6] + c1.z; o1.w = acc[7] + c1.w;
    *(float4*)&out[(size_t)node * 64 + fl * 8]     = o0;
    *(float4*)&out[(size_t)node * 64 + fl * 8 + 4] = o1;
  }
}

// ---------------------------------------------------------------- launch
extern "C" void kernel_launch(void* const* d_in, const int* in_sizes, int n_in,
                              void* d_out, int out_size, void* d_ws, size_t ws_size,
                              hipStream_t stream) {
  const float* x     = (const float*)d_in[0];
  const int*   edges = (const int*)d_in[1];
  const float* W1    = (const float*)d_in[2];
  const float* b1    = (const float*)d_in[3];
  const float* W2    = (const float*)d_in[4];
  const float* b2    = (const float*)d_in[5];
  float* out = (float*)d_out;

  // ---- workspace layout (R9-proven footprint)
  unsigned short* xb   = (unsigned short*)d_ws;            // NN*128 bf16
  unsigned short* h1b  = xb;                               // reuse after layer1 GEMM
  unsigned short* Hbuf = xb + (size_t)NN * 128;            // NR*NN*128 bf16
  unsigned short* Wt1  = Hbuf + (size_t)NR * NN * 128;     // NR*128*128 bf16
  unsigned short* Wt2  = Wt1 + (size_t)NR * 128 * 128;     // NR*64*128 bf16
  float* rs_out = (float*)(Wt2 + (size_t)NR * 64 * 128);   // NR*NN
  float* rs_in  = rs_out + (size_t)NR * NN;                // NR*NN
  int* cnt_out  = (int*)(rs_in + (size_t)NR * NN);         // NR*NN
  int* cnt_in   = cnt_out + (size_t)NR * NN;               // NR*NN
  int* row_ptr  = cnt_in + (size_t)NR * NN;                // NN+1
  int* cursor   = row_ptr + (NN + 1);                      // NN
  int* bsum     = cursor + NN;                             // 128
  float* bs1    = (float*)(bsum + 128);                    // 128
  float* bs2    = bs1 + 128;                               // 64
  int2* csr     = (int2*)(bs2 + 64);                       // NR*NE int2

  const int nb = (NN + SCAN_B - 1) / SCAN_B;  // 98

  // A) streaming prep: zero counters + cvtx + cvtw1 + cvtw2 + bias sums
  phaseA_k<<<A_NBLK, 256, 0, stream>>>(x, W1, W2, b1, b2, cnt_out, xb, Wt1, Wt2, bs1, bs2);
  // B) layer-1 GEMM (unscaled, z 0..3) co-resident with degree-count atomics
  phaseB_k<<<GEMMB + 2500, 256, 0, stream>>>(edges, xb, Wt1, Hbuf, cnt_out, cnt_in);
  // C) scans + rs arrays
  scan1_k<<<nb, 256, 0, stream>>>(cnt_in, cursor /*excl temp*/, bsum);
  scan2_k<<<1, 128, 0, stream>>>(bsum, nb);
  scan3rs_k<<<3125 + (NN + 255) / 256, 256, 0, stream>>>(cnt_out, rs_out, bsum, row_ptr, cursor);
  // D) CSR fill with combined edge weights (from proven rs arrays)
  fill_k<<<dim3((NE + 255) / 256, NR), 256, 0, stream>>>(edges, rs_out, rs_in, cursor, csr);
  // E) gather+bias+relu -> h1b
  gather1_k<<<(NN + 3) / 4, 256, 0, stream>>>(Hbuf, row_ptr, csr, bs1, h1b);
  // F) layer-2 GEMM (unscaled)
  gemm3_k<64><<<dim3(128, 1, NR), 256, 0, stream>>>(h1b, Wt2, Hbuf);
  // G) gather+bias -> out
  gather2_k<<<(NN + 3) / 4, 256, 0, stream>>>(Hbuf, row_ptr, csr, bs2, out);
}